// Round 1
// baseline (617.907 us; speedup 1.0000x reference)
//
#include <hip/hip_runtime.h>
#include <hip/hip_bf16.h>

#define B_ 8
#define N_ 512
#define NN (N_*N_)

// ---------------- zero the output (it is poisoned 0xAA before every launch) --
__global__ void k_zero(float* __restrict__ out, int n) {
    int i = blockIdx.x * 256 + threadIdx.x;
    if (i < n) out[i] = 0.0f;
}

// ---------------- node feature MLP: (B*N,3) -> 64 -> 128 --------------------
__global__ __launch_bounds__(128) void k_node_mlp(
    const float* __restrict__ coords,
    const float* __restrict__ fw0, const float* __restrict__ fb0,
    const float* __restrict__ fw1, const float* __restrict__ fb1,
    float* __restrict__ h)
{
    int row = blockIdx.x;          // 0..B*N-1
    int t = threadIdx.x;           // 0..127
    __shared__ float c[3];
    __shared__ float hid[64];
    if (t < 3) c[t] = coords[row * 3 + t];
    __syncthreads();
    if (t < 64) {
        float v = fb0[t];
        v += c[0] * fw0[0 * 64 + t];
        v += c[1] * fw0[1 * 64 + t];
        v += c[2] * fw0[2 * 64 + t];
        hid[t] = fmaxf(v, 0.0f);
    }
    __syncthreads();
    float acc = fb1[t];
#pragma unroll
    for (int k = 0; k < 64; ++k) acc += hid[k] * fw1[k * 128 + t];
    h[row * 128 + t] = fmaxf(acc, 0.0f);
}

// ---------------- adjacency MLP: one thread per (b,i,j) pair ----------------
// pair(6) -> 64 -> 64 -> 1, relu on every layer (incl. last).
// All weight loads are wave-uniform -> compiler emits s_load + SGPR-operand FMA.
__global__ __launch_bounds__(256) void k_adj(
    const float* __restrict__ coords,
    const float* __restrict__ aw0, const float* __restrict__ ab0,
    const float* __restrict__ aw1, const float* __restrict__ ab1,
    const float* __restrict__ aw2, const float* __restrict__ ab2,
    float* __restrict__ A)
{
    int p = blockIdx.x * 256 + threadIdx.x;   // 0 .. B*N*N-1 (exact grid)
    int b = p >> 18;                          // / (512*512)
    int rem = p & (NN - 1);
    int i = rem >> 9;
    int j = rem & (N_ - 1);

    const float* ci = coords + (size_t)(b * N_ + i) * 3;
    const float* cj = coords + (size_t)(b * N_ + j) * 3;
    float c0 = ci[0], c1 = ci[1], c2 = ci[2];
    float c3 = cj[0], c4 = cj[1], c5 = cj[2];

    float hid[64];
#pragma unroll
    for (int t = 0; t < 64; ++t) {
        float v = ab0[t];
        v += c0 * aw0[0 * 64 + t];
        v += c1 * aw0[1 * 64 + t];
        v += c2 * aw0[2 * 64 + t];
        v += c3 * aw0[3 * 64 + t];
        v += c4 * aw0[4 * 64 + t];
        v += c5 * aw0[5 * 64 + t];
        hid[t] = fmaxf(v, 0.0f);
    }

    float acc = ab2[0];
#pragma unroll 1
    for (int k = 0; k < 64; k += 8) {
        float h2[8];
#pragma unroll
        for (int u = 0; u < 8; ++u) h2[u] = ab1[k + u];
#pragma unroll
        for (int m = 0; m < 64; ++m) {
            float hm = hid[m];
#pragma unroll
            for (int u = 0; u < 8; ++u) h2[u] += hm * aw1[m * 64 + k + u];
        }
#pragma unroll
        for (int u = 0; u < 8; ++u) acc += fmaxf(h2[u], 0.0f) * aw2[k + u];
    }
    A[p] = fmaxf(acc, 0.0f);
}

// ---------------- V = A @ h : per (b,i) row, 128 channels -------------------
__global__ __launch_bounds__(128) void k_aggregate(
    const float* __restrict__ A, const float* __restrict__ h,
    float* __restrict__ V)
{
    int row = blockIdx.x;          // b*N + i
    int b = row >> 9;
    int t = threadIdx.x;           // 0..127
    const float* Arow = A + (size_t)row * N_;
    const float* hb = h + (size_t)b * N_ * 128;
    float acc0 = 0.f, acc1 = 0.f, acc2 = 0.f, acc3 = 0.f;
#pragma unroll 1
    for (int j = 0; j < N_; j += 4) {
        acc0 += Arow[j + 0] * hb[(size_t)(j + 0) * 128 + t];
        acc1 += Arow[j + 1] * hb[(size_t)(j + 1) * 128 + t];
        acc2 += Arow[j + 2] * hb[(size_t)(j + 2) * 128 + t];
        acc3 += Arow[j + 3] * hb[(size_t)(j + 3) * 128 + t];
    }
    V[(size_t)row * 128 + t] = (acc0 + acc1) + (acc2 + acc3);
}

// ---------------- update MLP (259 -> 256 -> 128) + max pool -----------------
__global__ __launch_bounds__(256) void k_update(
    const float* __restrict__ h, const float* __restrict__ coords,
    const float* __restrict__ V,
    const float* __restrict__ uw0, const float* __restrict__ ub0,
    const float* __restrict__ uw1, const float* __restrict__ ub1,
    float* __restrict__ out)
{
    int row = blockIdx.x;          // b*N + n
    int b = row >> 9;
    int t = threadIdx.x;           // 0..255

    __shared__ float upd[259];
    __shared__ float u1[256];

    if (t < 128) {
        upd[t] = h[(size_t)row * 128 + t];
        upd[131 + t] = V[(size_t)row * 128 + t];
    } else if (t < 131) {
        upd[t] = coords[(size_t)row * 3 + (t - 128)];
    }
    __syncthreads();

    float acc = ub0[t];
#pragma unroll 1
    for (int k = 0; k < 259; ++k) acc += upd[k] * uw0[k * 256 + t];
    u1[t] = fmaxf(acc, 0.0f);
    __syncthreads();

    if (t < 128) {
        float a2 = ub1[t];
#pragma unroll 1
        for (int k = 0; k < 256; ++k) a2 += u1[k] * uw1[k * 128 + t];
        a2 = fmaxf(a2, 0.0f);
        // final relu => a2 >= 0, int compare == float compare for non-negatives
        atomicMax((int*)(out + (size_t)b * 128 + t), __float_as_int(a2));
    }
}

extern "C" void kernel_launch(void* const* d_in, const int* in_sizes, int n_in,
                              void* d_out, int out_size, void* d_ws, size_t ws_size,
                              hipStream_t stream)
{
    const float* coords = (const float*)d_in[0];
    const float* fw0 = (const float*)d_in[1];
    const float* fb0 = (const float*)d_in[2];
    const float* fw1 = (const float*)d_in[3];
    const float* fb1 = (const float*)d_in[4];
    const float* aw0 = (const float*)d_in[5];
    const float* ab0 = (const float*)d_in[6];
    const float* aw1 = (const float*)d_in[7];
    const float* ab1 = (const float*)d_in[8];
    const float* aw2 = (const float*)d_in[9];
    const float* ab2 = (const float*)d_in[10];
    const float* uw0 = (const float*)d_in[11];
    const float* ub0 = (const float*)d_in[12];
    const float* uw1 = (const float*)d_in[13];
    const float* ub1 = (const float*)d_in[14];
    float* out = (float*)d_out;

    // workspace layout
    char* ws = (char*)d_ws;
    float* h = (float*)(ws);                                // B*N*128 = 2 MB
    float* A = (float*)(ws + (size_t)B_ * N_ * 128 * 4);    // B*N*N   = 8 MB
    float* V = (float*)(ws + (size_t)B_ * N_ * 128 * 4 + (size_t)B_ * NN * 4); // 2 MB

    k_zero<<<(out_size + 255) / 256, 256, 0, stream>>>(out, out_size);
    k_node_mlp<<<B_ * N_, 128, 0, stream>>>(coords, fw0, fb0, fw1, fb1, h);
    k_adj<<<(B_ * NN) / 256, 256, 0, stream>>>(coords, aw0, ab0, aw1, ab1, aw2, ab2, A);
    k_aggregate<<<B_ * N_, 128, 0, stream>>>(A, h, V);
    k_update<<<B_ * N_, 256, 0, stream>>>(h, coords, V, uw0, ub0, uw1, ub1, out);
}

// Round 2
// 317.910 us; speedup vs baseline: 1.9437x; 1.9437x over previous
//
#include <hip/hip_runtime.h>
#include <hip/hip_bf16.h>

#define B_ 8
#define N_ 512
#define NN (N_*N_)

typedef __attribute__((ext_vector_type(8))) __bf16 bf16x8;
typedef __attribute__((ext_vector_type(4))) float f32x4;

// ---------------- zero the output (poisoned 0xAA before every launch) -------
__global__ void k_zero(float* __restrict__ out, int n) {
    int i = blockIdx.x * 256 + threadIdx.x;
    if (i < n) out[i] = 0.0f;
}

// ---------------- node feature MLP: (B*N,3) -> 64 -> 128 --------------------
__global__ __launch_bounds__(128) void k_node_mlp(
    const float* __restrict__ coords,
    const float* __restrict__ fw0, const float* __restrict__ fb0,
    const float* __restrict__ fw1, const float* __restrict__ fb1,
    float* __restrict__ h)
{
    int row = blockIdx.x;          // 0..B*N-1
    int t = threadIdx.x;           // 0..127
    __shared__ float c[3];
    __shared__ float hid[64];
    if (t < 3) c[t] = coords[row * 3 + t];
    __syncthreads();
    if (t < 64) {
        float v = fb0[t];
        v += c[0] * fw0[0 * 64 + t];
        v += c[1] * fw0[1 * 64 + t];
        v += c[2] * fw0[2 * 64 + t];
        hid[t] = fmaxf(v, 0.0f);
    }
    __syncthreads();
    float acc = fb1[t];
#pragma unroll
    for (int k = 0; k < 64; ++k) acc += hid[k] * fw1[k * 128 + t];
    h[row * 128 + t] = fmaxf(acc, 0.0f);
}

// ---------------- adjacency MLP via bf16 MFMA -------------------------------
// pair(6) -> 64 -> 64 -> 1, relu everywhere (incl. last layer).
// Layer 0: VALU fp32 (c_i part folded into per-wave o_i), pack to bf16.
// Layer 1 (64x64, 90% of FLOPs): mfma_f32_16x16x32_bf16, A = h1 tile (16 pairs
//   x 32 k), B = aw1 (bf16, preloaded in 8 fragments).
// Layer 2: in C-layout: p += relu(C + ab1)*aw2, shfl_xor reduce over 16 cols.
// Block = 256 thr (4 waves), wave w handles i = (blk&127)*4 + w; 32 tiles of 16 j.
__global__ __launch_bounds__(256) void k_adj(
    const float* __restrict__ coords,
    const float* __restrict__ aw0, const float* __restrict__ ab0,
    const float* __restrict__ aw1, const float* __restrict__ ab1,
    const float* __restrict__ aw2, const float* __restrict__ ab2,
    float* __restrict__ A)
{
    const int tid = threadIdx.x;
    const int l = tid & 63;          // lane
    const int wave = tid >> 6;       // 0..3
    const int q = l >> 4;            // quad 0..3
    const int m = l & 15;            // 0..15
    const int b = blockIdx.x >> 7;
    const int i = ((blockIdx.x & 127) << 2) + wave;

    // wave-uniform c_i
    const float* ci = coords + (size_t)(b * N_ + i) * 3;
    const float ci0 = ci[0], ci1 = ci[1], ci2 = ci[2];

    // per-lane layer-0 constants for channels c = s*32 + q*8 + j
    float o[2][8], w3[2][8], w4[2][8], w5[2][8];
#pragma unroll
    for (int s = 0; s < 2; ++s)
#pragma unroll
        for (int j = 0; j < 8; ++j) {
            int c = s * 32 + q * 8 + j;
            o[s][j] = ab0[c] + ci0 * aw0[0 * 64 + c] + ci1 * aw0[1 * 64 + c]
                             + ci2 * aw0[2 * 64 + c];
            w3[s][j] = aw0[3 * 64 + c];
            w4[s][j] = aw0[4 * 64 + c];
            w5[s][j] = aw0[5 * 64 + c];
        }

    // B fragments: bf[s][ct] holds aw1[k = s*32+q*8+j][n = ct*16+m]
    bf16x8 bf[2][4];
#pragma unroll
    for (int s = 0; s < 2; ++s)
#pragma unroll
        for (int ct = 0; ct < 4; ++ct)
#pragma unroll
            for (int j = 0; j < 8; ++j)
                bf[s][ct][j] = (__bf16)aw1[(s * 32 + q * 8 + j) * 64 + ct * 16 + m];

    float ab1v[4], aw2v[4];
#pragma unroll
    for (int ct = 0; ct < 4; ++ct) {
        ab1v[ct] = ab1[ct * 16 + m];
        aw2v[ct] = aw2[ct * 16 + m];
    }
    const float ab2s = ab2[0];

    float* Arow = A + ((size_t)(b * N_ + i) << 9);

#pragma unroll 1
    for (int t = 0; t < 32; ++t) {
        int j0 = t << 4;
        const float* cj = coords + (size_t)(b * N_ + j0 + m) * 3;
        float d0 = cj[0], d1 = cj[1], d2 = cj[2];

        bf16x8 a0, a1;
#pragma unroll
        for (int j = 0; j < 8; ++j) {
            float v0 = fmaxf(o[0][j] + d0 * w3[0][j] + d1 * w4[0][j] + d2 * w5[0][j], 0.0f);
            float v1 = fmaxf(o[1][j] + d0 * w3[1][j] + d1 * w4[1][j] + d2 * w5[1][j], 0.0f);
            a0[j] = (__bf16)v0;
            a1[j] = (__bf16)v1;
        }

        float p0 = 0.f, p1 = 0.f, p2 = 0.f, p3 = 0.f;
#pragma unroll
        for (int ct = 0; ct < 4; ++ct) {
            f32x4 c = {0.f, 0.f, 0.f, 0.f};
            c = __builtin_amdgcn_mfma_f32_16x16x32_bf16(a0, bf[0][ct], c, 0, 0, 0);
            c = __builtin_amdgcn_mfma_f32_16x16x32_bf16(a1, bf[1][ct], c, 0, 0, 0);
            p0 += fmaxf(c[0] + ab1v[ct], 0.0f) * aw2v[ct];
            p1 += fmaxf(c[1] + ab1v[ct], 0.0f) * aw2v[ct];
            p2 += fmaxf(c[2] + ab1v[ct], 0.0f) * aw2v[ct];
            p3 += fmaxf(c[3] + ab1v[ct], 0.0f) * aw2v[ct];
        }
        // sum over the 16 columns (lanes within the 16-lane group)
#pragma unroll
        for (int mask = 1; mask < 16; mask <<= 1) {
            p0 += __shfl_xor(p0, mask, 16);
            p1 += __shfl_xor(p1, mask, 16);
            p2 += __shfl_xor(p2, mask, 16);
            p3 += __shfl_xor(p3, mask, 16);
        }
        if (m == 0) {
            // rows held by this quad: pairs j0 + q*4 + {0..3}
            f32x4 outv;
            outv[0] = fmaxf(ab2s + p0, 0.0f);
            outv[1] = fmaxf(ab2s + p1, 0.0f);
            outv[2] = fmaxf(ab2s + p2, 0.0f);
            outv[3] = fmaxf(ab2s + p3, 0.0f);
            *(f32x4*)(Arow + j0 + q * 4) = outv;
        }
    }
}

// ---------------- V = A @ h : 4 rows per block, h reads shared --------------
__global__ __launch_bounds__(128) void k_aggregate(
    const float* __restrict__ A, const float* __restrict__ h,
    float* __restrict__ V)
{
    int row0 = blockIdx.x << 2;    // 4 rows, same b (512 % 4 == 0)
    int b = row0 >> 9;
    int t = threadIdx.x;           // 0..127
    const float* hb = h + ((size_t)b * N_ << 7);
    const float* A0 = A + ((size_t)row0 << 9);
    float a0 = 0.f, a1 = 0.f, a2 = 0.f, a3 = 0.f;
#pragma unroll 4
    for (int j = 0; j < N_; ++j) {
        float hv = hb[(j << 7) + t];
        a0 += A0[j] * hv;
        a1 += A0[N_ + j] * hv;
        a2 += A0[2 * N_ + j] * hv;
        a3 += A0[3 * N_ + j] * hv;
    }
    V[((size_t)row0 << 7) + t] = a0;
    V[((size_t)(row0 + 1) << 7) + t] = a1;
    V[((size_t)(row0 + 2) << 7) + t] = a2;
    V[((size_t)(row0 + 3) << 7) + t] = a3;
}

// ---------------- update MLP (259 -> 256 -> 128) + max pool, 4 rows/block ---
__global__ __launch_bounds__(256) void k_update(
    const float* __restrict__ h, const float* __restrict__ coords,
    const float* __restrict__ V,
    const float* __restrict__ uw0, const float* __restrict__ ub0,
    const float* __restrict__ uw1, const float* __restrict__ ub1,
    float* __restrict__ out)
{
    int row0 = blockIdx.x << 2;    // 4 rows, same b
    int b = row0 >> 9;
    int t = threadIdx.x;           // 0..255

    __shared__ float upd[4][260];
    __shared__ float u1[4][256];

#pragma unroll
    for (int r = 0; r < 4; ++r) {
        int row = row0 + r;
        if (t < 128) {
            upd[r][t] = h[((size_t)row << 7) + t];
            upd[r][131 + t] = V[((size_t)row << 7) + t];
        } else if (t < 131) {
            upd[r][t] = coords[(size_t)row * 3 + (t - 128)];
        }
    }
    __syncthreads();

    float acc0 = ub0[t], acc1 = acc0, acc2 = acc0, acc3 = acc0;
#pragma unroll 1
    for (int k = 0; k < 259; ++k) {
        float w = uw0[k * 256 + t];
        acc0 += upd[0][k] * w;
        acc1 += upd[1][k] * w;
        acc2 += upd[2][k] * w;
        acc3 += upd[3][k] * w;
    }
    u1[0][t] = fmaxf(acc0, 0.0f);
    u1[1][t] = fmaxf(acc1, 0.0f);
    u1[2][t] = fmaxf(acc2, 0.0f);
    u1[3][t] = fmaxf(acc3, 0.0f);
    __syncthreads();

    if (t < 128) {
        float a0 = ub1[t], a1 = a0, a2 = a0, a3 = a0;
#pragma unroll 1
        for (int k = 0; k < 256; ++k) {
            float w = uw1[k * 128 + t];
            a0 += u1[0][k] * w;
            a1 += u1[1][k] * w;
            a2 += u1[2][k] * w;
            a3 += u1[3][k] * w;
        }
        int* o = (int*)(out + ((size_t)b << 7) + t);
        atomicMax(o, __float_as_int(fmaxf(a0, 0.0f)));
        atomicMax(o, __float_as_int(fmaxf(a1, 0.0f)));
        atomicMax(o, __float_as_int(fmaxf(a2, 0.0f)));
        atomicMax(o, __float_as_int(fmaxf(a3, 0.0f)));
    }
}

extern "C" void kernel_launch(void* const* d_in, const int* in_sizes, int n_in,
                              void* d_out, int out_size, void* d_ws, size_t ws_size,
                              hipStream_t stream)
{
    const float* coords = (const float*)d_in[0];
    const float* fw0 = (const float*)d_in[1];
    const float* fb0 = (const float*)d_in[2];
    const float* fw1 = (const float*)d_in[3];
    const float* fb1 = (const float*)d_in[4];
    const float* aw0 = (const float*)d_in[5];
    const float* ab0 = (const float*)d_in[6];
    const float* aw1 = (const float*)d_in[7];
    const float* ab1 = (const float*)d_in[8];
    const float* aw2 = (const float*)d_in[9];
    const float* ab2 = (const float*)d_in[10];
    const float* uw0 = (const float*)d_in[11];
    const float* ub0 = (const float*)d_in[12];
    const float* uw1 = (const float*)d_in[13];
    const float* ub1 = (const float*)d_in[14];
    float* out = (float*)d_out;

    // workspace layout
    char* ws = (char*)d_ws;
    float* h = (float*)(ws);                                // B*N*128 = 2 MB
    float* A = (float*)(ws + (size_t)B_ * N_ * 128 * 4);    // B*N*N   = 8 MB
    float* V = (float*)(ws + (size_t)B_ * N_ * 128 * 4 + (size_t)B_ * NN * 4); // 2 MB

    k_zero<<<(out_size + 255) / 256, 256, 0, stream>>>(out, out_size);
    k_node_mlp<<<B_ * N_, 128, 0, stream>>>(coords, fw0, fb0, fw1, fb1, h);
    k_adj<<<B_ * N_ / 4, 256, 0, stream>>>(coords, aw0, ab0, aw1, ab1, aw2, ab2, A);
    k_aggregate<<<B_ * N_ / 4, 128, 0, stream>>>(A, h, V);
    k_update<<<B_ * N_ / 4, 256, 0, stream>>>(h, coords, V, uw0, ub0, uw1, ub1, out);
}

// Round 3
// 220.621 us; speedup vs baseline: 2.8008x; 1.4410x over previous
//
#include <hip/hip_runtime.h>
#include <hip/hip_bf16.h>

#define B_ 8
#define N_ 512
#define NN (N_*N_)

typedef __attribute__((ext_vector_type(8))) __bf16 bf16x8;
typedef __attribute__((ext_vector_type(4))) float f32x4;

// ---------------- zero the output (poisoned 0xAA before every launch) -------
__global__ void k_zero(float* __restrict__ out, int n) {
    int i = blockIdx.x * 256 + threadIdx.x;
    if (i < n) out[i] = 0.0f;
}

// ---------------- node feature MLP: (B*N,3) -> 64 -> 128 --------------------
__global__ __launch_bounds__(128) void k_node_mlp(
    const float* __restrict__ coords,
    const float* __restrict__ fw0, const float* __restrict__ fb0,
    const float* __restrict__ fw1, const float* __restrict__ fb1,
    float* __restrict__ h)
{
    int row = blockIdx.x;          // 0..B*N-1
    int t = threadIdx.x;           // 0..127
    __shared__ float c[3];
    __shared__ float hid[64];
    if (t < 3) c[t] = coords[row * 3 + t];
    __syncthreads();
    if (t < 64) {
        float v = fb0[t];
        v += c[0] * fw0[0 * 64 + t];
        v += c[1] * fw0[1 * 64 + t];
        v += c[2] * fw0[2 * 64 + t];
        hid[t] = fmaxf(v, 0.0f);
    }
    __syncthreads();
    float acc = fb1[t];
#pragma unroll
    for (int k = 0; k < 64; ++k) acc += hid[k] * fw1[k * 128 + t];
    h[row * 128 + t] = fmaxf(acc, 0.0f);
}

// ---------------- adjacency MLP via bf16 MFMA (unchanged from R2) -----------
__global__ __launch_bounds__(256) void k_adj(
    const float* __restrict__ coords,
    const float* __restrict__ aw0, const float* __restrict__ ab0,
    const float* __restrict__ aw1, const float* __restrict__ ab1,
    const float* __restrict__ aw2, const float* __restrict__ ab2,
    float* __restrict__ A)
{
    const int tid = threadIdx.x;
    const int l = tid & 63;          // lane
    const int wave = tid >> 6;       // 0..3
    const int q = l >> 4;            // quad 0..3
    const int m = l & 15;            // 0..15
    const int b = blockIdx.x >> 7;
    const int i = ((blockIdx.x & 127) << 2) + wave;

    const float* ci = coords + (size_t)(b * N_ + i) * 3;
    const float ci0 = ci[0], ci1 = ci[1], ci2 = ci[2];

    float o[2][8], w3[2][8], w4[2][8], w5[2][8];
#pragma unroll
    for (int s = 0; s < 2; ++s)
#pragma unroll
        for (int j = 0; j < 8; ++j) {
            int c = s * 32 + q * 8 + j;
            o[s][j] = ab0[c] + ci0 * aw0[0 * 64 + c] + ci1 * aw0[1 * 64 + c]
                             + ci2 * aw0[2 * 64 + c];
            w3[s][j] = aw0[3 * 64 + c];
            w4[s][j] = aw0[4 * 64 + c];
            w5[s][j] = aw0[5 * 64 + c];
        }

    bf16x8 bf[2][4];
#pragma unroll
    for (int s = 0; s < 2; ++s)
#pragma unroll
        for (int ct = 0; ct < 4; ++ct)
#pragma unroll
            for (int j = 0; j < 8; ++j)
                bf[s][ct][j] = (__bf16)aw1[(s * 32 + q * 8 + j) * 64 + ct * 16 + m];

    float ab1v[4], aw2v[4];
#pragma unroll
    for (int ct = 0; ct < 4; ++ct) {
        ab1v[ct] = ab1[ct * 16 + m];
        aw2v[ct] = aw2[ct * 16 + m];
    }
    const float ab2s = ab2[0];

    float* Arow = A + ((size_t)(b * N_ + i) << 9);

#pragma unroll 1
    for (int t = 0; t < 32; ++t) {
        int j0 = t << 4;
        const float* cj = coords + (size_t)(b * N_ + j0 + m) * 3;
        float d0 = cj[0], d1 = cj[1], d2 = cj[2];

        bf16x8 a0, a1;
#pragma unroll
        for (int j = 0; j < 8; ++j) {
            float v0 = fmaxf(o[0][j] + d0 * w3[0][j] + d1 * w4[0][j] + d2 * w5[0][j], 0.0f);
            float v1 = fmaxf(o[1][j] + d0 * w3[1][j] + d1 * w4[1][j] + d2 * w5[1][j], 0.0f);
            a0[j] = (__bf16)v0;
            a1[j] = (__bf16)v1;
        }

        float p0 = 0.f, p1 = 0.f, p2 = 0.f, p3 = 0.f;
#pragma unroll
        for (int ct = 0; ct < 4; ++ct) {
            f32x4 c = {0.f, 0.f, 0.f, 0.f};
            c = __builtin_amdgcn_mfma_f32_16x16x32_bf16(a0, bf[0][ct], c, 0, 0, 0);
            c = __builtin_amdgcn_mfma_f32_16x16x32_bf16(a1, bf[1][ct], c, 0, 0, 0);
            p0 += fmaxf(c[0] + ab1v[ct], 0.0f) * aw2v[ct];
            p1 += fmaxf(c[1] + ab1v[ct], 0.0f) * aw2v[ct];
            p2 += fmaxf(c[2] + ab1v[ct], 0.0f) * aw2v[ct];
            p3 += fmaxf(c[3] + ab1v[ct], 0.0f) * aw2v[ct];
        }
#pragma unroll
        for (int mask = 1; mask < 16; mask <<= 1) {
            p0 += __shfl_xor(p0, mask, 16);
            p1 += __shfl_xor(p1, mask, 16);
            p2 += __shfl_xor(p2, mask, 16);
            p3 += __shfl_xor(p3, mask, 16);
        }
        if (m == 0) {
            f32x4 outv;
            outv[0] = fmaxf(ab2s + p0, 0.0f);
            outv[1] = fmaxf(ab2s + p1, 0.0f);
            outv[2] = fmaxf(ab2s + p2, 0.0f);
            outv[3] = fmaxf(ab2s + p3, 0.0f);
            *(f32x4*)(Arow + j0 + q * 4) = outv;
        }
    }
}

// ---------------- V = A @ h : 4 rows per block, h reads shared --------------
__global__ __launch_bounds__(128) void k_aggregate(
    const float* __restrict__ A, const float* __restrict__ h,
    float* __restrict__ V)
{
    int row0 = blockIdx.x << 2;    // 4 rows, same b (512 % 4 == 0)
    int b = row0 >> 9;
    int t = threadIdx.x;           // 0..127
    const float* hb = h + ((size_t)b * N_ << 7);
    const float* A0 = A + ((size_t)row0 << 9);
    float a0 = 0.f, a1 = 0.f, a2 = 0.f, a3 = 0.f;
#pragma unroll 4
    for (int j = 0; j < N_; ++j) {
        float hv = hb[(j << 7) + t];
        a0 += A0[j] * hv;
        a1 += A0[N_ + j] * hv;
        a2 += A0[2 * N_ + j] * hv;
        a3 += A0[3 * N_ + j] * hv;
    }
    V[((size_t)row0 << 7) + t] = a0;
    V[((size_t)(row0 + 1) << 7) + t] = a1;
    V[((size_t)(row0 + 2) << 7) + t] = a2;
    V[((size_t)(row0 + 3) << 7) + t] = a3;
}

// ---------------- update MLP (259 -> 256 -> 128) + max pool -----------------
// 16 rows/block, 256 blocks. Wave g owns rows 4g..4g+3; lane l owns 4 cols.
// Weights: float4 global loads, 4 k-steps in flight. Activations: broadcast
// ds_read_b128 (wave-uniform address -> conflict-free). 64 FMA per 4-k step.
__global__ __launch_bounds__(256) void k_update(
    const float* __restrict__ h, const float* __restrict__ coords,
    const float* __restrict__ V,
    const float* __restrict__ uw0, const float* __restrict__ ub0,
    const float* __restrict__ uw1, const float* __restrict__ ub1,
    float* __restrict__ out)
{
    const int t = threadIdx.x;
    const int g = t >> 6;            // wave = row group
    const int l = t & 63;
    const int row0 = blockIdx.x << 4;   // 16 rows, all same b (512%16==0)
    const int b = row0 >> 9;

    __shared__ float upd[16][260];   // row stride 1040 B (16B aligned)
    __shared__ float u1[16][260];

#pragma unroll 1
    for (int r = 0; r < 16; ++r) {
        int row = row0 + r;
        if (t < 128) {
            upd[r][t] = h[((size_t)row << 7) + t];
            upd[r][131 + t] = V[((size_t)row << 7) + t];
        } else if (t < 131) {
            upd[r][t] = coords[(size_t)row * 3 + (t - 128)];
        }
    }
    __syncthreads();

    // ---- layer 1: cols c0=4l..4l+3, rows rg=4g..4g+3 ----
    const int c0 = l << 2;
    const int rg = g << 2;
    float acc[4][4];
#pragma unroll
    for (int c = 0; c < 4; ++c) {
        float bias = ub0[c0 + c];
#pragma unroll
        for (int r = 0; r < 4; ++r) acc[r][c] = bias;
    }

#pragma unroll 2
    for (int k = 0; k < 256; k += 4) {
        float4 w[4];
#pragma unroll
        for (int kk = 0; kk < 4; ++kk)
            w[kk] = *(const float4*)(uw0 + (size_t)(k + kk) * 256 + c0);
        float4 u[4];
#pragma unroll
        for (int r = 0; r < 4; ++r)
            u[r] = *(const float4*)&upd[rg + r][k];
#pragma unroll
        for (int r = 0; r < 4; ++r) {
            acc[r][0] += u[r].x * w[0].x + u[r].y * w[1].x + u[r].z * w[2].x + u[r].w * w[3].x;
            acc[r][1] += u[r].x * w[0].y + u[r].y * w[1].y + u[r].z * w[2].y + u[r].w * w[3].y;
            acc[r][2] += u[r].x * w[0].z + u[r].y * w[1].z + u[r].z * w[2].z + u[r].w * w[3].z;
            acc[r][3] += u[r].x * w[0].w + u[r].y * w[1].w + u[r].z * w[2].w + u[r].w * w[3].w;
        }
    }
    // tail k = 256..258
#pragma unroll
    for (int k = 256; k < 259; ++k) {
        float4 w = *(const float4*)(uw0 + (size_t)k * 256 + c0);
#pragma unroll
        for (int r = 0; r < 4; ++r) {
            float uv = upd[rg + r][k];
            acc[r][0] += uv * w.x;
            acc[r][1] += uv * w.y;
            acc[r][2] += uv * w.z;
            acc[r][3] += uv * w.w;
        }
    }
#pragma unroll
    for (int r = 0; r < 4; ++r) {
        float4 v;
        v.x = fmaxf(acc[r][0], 0.0f);
        v.y = fmaxf(acc[r][1], 0.0f);
        v.z = fmaxf(acc[r][2], 0.0f);
        v.w = fmaxf(acc[r][3], 0.0f);
        *(float4*)&u1[rg + r][c0] = v;
    }
    __syncthreads();

    // ---- layer 2: cols c=2l,2l+1, rows rg..rg+3 ----
    const int c2 = l << 1;
    float a2[4][2];
    {
        float b0 = ub1[c2], b1v = ub1[c2 + 1];
#pragma unroll
        for (int r = 0; r < 4; ++r) { a2[r][0] = b0; a2[r][1] = b1v; }
    }
#pragma unroll 2
    for (int k = 0; k < 256; k += 4) {
        float2 w[4];
#pragma unroll
        for (int kk = 0; kk < 4; ++kk)
            w[kk] = *(const float2*)(uw1 + (size_t)(k + kk) * 128 + c2);
        float4 u[4];
#pragma unroll
        for (int r = 0; r < 4; ++r)
            u[r] = *(const float4*)&u1[rg + r][k];
#pragma unroll
        for (int r = 0; r < 4; ++r) {
            a2[r][0] += u[r].x * w[0].x + u[r].y * w[1].x + u[r].z * w[2].x + u[r].w * w[3].x;
            a2[r][1] += u[r].x * w[0].y + u[r].y * w[1].y + u[r].z * w[2].y + u[r].w * w[3].y;
        }
    }
    // per-thread max over its 4 rows (relu'd)
    float m0 = 0.0f, m1 = 0.0f;
#pragma unroll
    for (int r = 0; r < 4; ++r) {
        m0 = fmaxf(m0, a2[r][0]);
        m1 = fmaxf(m1, a2[r][1]);
    }
    m0 = fmaxf(m0, 0.0f); m1 = fmaxf(m1, 0.0f);
    __syncthreads();
    // cross-wave reduce in LDS (reuse upd), then one atomic per col per block
    float* red = &upd[0][0];         // need 4*128 floats
    red[g * 130 + c2] = m0;
    red[g * 130 + c2 + 1] = m1;
    __syncthreads();
    if (t < 128) {
        float mx = fmaxf(fmaxf(red[t], red[130 + t]),
                         fmaxf(red[260 + t], red[390 + t]));
        atomicMax((int*)(out + ((size_t)b << 7) + t), __float_as_int(mx));
    }
}

extern "C" void kernel_launch(void* const* d_in, const int* in_sizes, int n_in,
                              void* d_out, int out_size, void* d_ws, size_t ws_size,
                              hipStream_t stream)
{
    const float* coords = (const float*)d_in[0];
    const float* fw0 = (const float*)d_in[1];
    const float* fb0 = (const float*)d_in[2];
    const float* fw1 = (const float*)d_in[3];
    const float* fb1 = (const float*)d_in[4];
    const float* aw0 = (const float*)d_in[5];
    const float* ab0 = (const float*)d_in[6];
    const float* aw1 = (const float*)d_in[7];
    const float* ab1 = (const float*)d_in[8];
    const float* aw2 = (const float*)d_in[9];
    const float* ab2 = (const float*)d_in[10];
    const float* uw0 = (const float*)d_in[11];
    const float* ub0 = (const float*)d_in[12];
    const float* uw1 = (const float*)d_in[13];
    const float* ub1 = (const float*)d_in[14];
    float* out = (float*)d_out;

    // workspace layout
    char* ws = (char*)d_ws;
    float* h = (float*)(ws);                                // B*N*128 = 2 MB
    float* A = (float*)(ws + (size_t)B_ * N_ * 128 * 4);    // B*N*N   = 8 MB
    float* V = (float*)(ws + (size_t)B_ * N_ * 128 * 4 + (size_t)B_ * NN * 4); // 2 MB

    k_zero<<<(out_size + 255) / 256, 256, 0, stream>>>(out, out_size);
    k_node_mlp<<<B_ * N_, 128, 0, stream>>>(coords, fw0, fb0, fw1, fb1, h);
    k_adj<<<B_ * N_ / 4, 256, 0, stream>>>(coords, aw0, ab0, aw1, ab1, aw2, ab2, A);
    k_aggregate<<<B_ * N_ / 4, 128, 0, stream>>>(A, h, V);
    k_update<<<B_ * N_ / 16, 256, 0, stream>>>(h, coords, V, uw0, ub0, uw1, ub1, out);
}

// Round 4
// 208.062 us; speedup vs baseline: 2.9698x; 1.0604x over previous
//
#include <hip/hip_runtime.h>
#include <hip/hip_bf16.h>

#define B_ 8
#define N_ 512
#define NN (N_*N_)

typedef __attribute__((ext_vector_type(8))) __bf16 bf16x8;
typedef __attribute__((ext_vector_type(4))) float f32x4;

// ---------------- zero the output (poisoned 0xAA before every launch) -------
__global__ void k_zero(float* __restrict__ out, int n) {
    int i = blockIdx.x * 256 + threadIdx.x;
    if (i < n) out[i] = 0.0f;
}

// ---------------- node feature MLP: (B*N,3) -> 64 -> 128 --------------------
// writes h fp32 (for update concat) AND h^T bf16 (B-operand for aggregate MFMA)
__global__ __launch_bounds__(128) void k_node_mlp(
    const float* __restrict__ coords,
    const float* __restrict__ fw0, const float* __restrict__ fb0,
    const float* __restrict__ fw1, const float* __restrict__ fb1,
    float* __restrict__ h, __bf16* __restrict__ h_t)
{
    int row = blockIdx.x;          // b*512 + n
    int b = row >> 9;
    int n = row & 511;
    int t = threadIdx.x;           // 0..127
    __shared__ float c[3];
    __shared__ float hid[64];
    if (t < 3) c[t] = coords[row * 3 + t];
    __syncthreads();
    if (t < 64) {
        float v = fb0[t];
        v += c[0] * fw0[0 * 64 + t];
        v += c[1] * fw0[1 * 64 + t];
        v += c[2] * fw0[2 * 64 + t];
        hid[t] = fmaxf(v, 0.0f);
    }
    __syncthreads();
    float acc = fb1[t];
#pragma unroll
    for (int k = 0; k < 64; ++k) acc += hid[k] * fw1[k * 128 + t];
    float r = fmaxf(acc, 0.0f);
    h[(size_t)row * 128 + t] = r;
    h_t[(size_t)(b * 128 + t) * 512 + n] = (__bf16)r;
}

// ---------------- adjacency MLP via bf16 MFMA, transposed epilogue ----------
// pair(6) -> 64 -> 64 -> 1, relu everywhere.
// Layer 1 MFMA computes H2^T: A-op = aw1^T fragments, B-op = h1 fragments
// (identical lane maps to R3's fragments, operands swapped). Lane then holds
// 16 output channels for ONE pair -> layer-2 dot is in-register; reduce is
// only 2 shfl steps across quads. ab1 folded into MFMA C-init.
// A output written in bf16 (consumed only by the aggregate MFMA GEMM).
__global__ __launch_bounds__(256) void k_adj(
    const float* __restrict__ coords,
    const float* __restrict__ aw0, const float* __restrict__ ab0,
    const float* __restrict__ aw1, const float* __restrict__ ab1,
    const float* __restrict__ aw2, const float* __restrict__ ab2,
    __bf16* __restrict__ A)
{
    const int tid = threadIdx.x;
    const int l = tid & 63;          // lane
    const int wave = tid >> 6;       // 0..3
    const int q = l >> 4;            // quad 0..3
    const int m = l & 15;            // 0..15
    const int b = blockIdx.x >> 7;
    const int i = ((blockIdx.x & 127) << 2) + wave;

    // wave-uniform c_i, folded into layer-0 bias
    const float* ci = coords + (size_t)(b * N_ + i) * 3;
    const float ci0 = ci[0], ci1 = ci[1], ci2 = ci[2];

    float o[2][8], w3[2][8], w4[2][8], w5[2][8];
#pragma unroll
    for (int s = 0; s < 2; ++s)
#pragma unroll
        for (int j = 0; j < 8; ++j) {
            int c = s * 32 + q * 8 + j;
            o[s][j] = ab0[c] + ci0 * aw0[0 * 64 + c] + ci1 * aw0[1 * 64 + c]
                             + ci2 * aw0[2 * 64 + c];
            w3[s][j] = aw0[3 * 64 + c];
            w4[s][j] = aw0[4 * 64 + c];
            w5[s][j] = aw0[5 * 64 + c];
        }

    // aw1 fragments: bf[s][ct][j] = aw1[k=s*32+q*8+j][ct*16+m]
    // used as A-operand: A'[m][k] = aw1^T tile (rows = out-ch ct*16+m)
    bf16x8 bf[2][4];
#pragma unroll
    for (int s = 0; s < 2; ++s)
#pragma unroll
        for (int ct = 0; ct < 4; ++ct)
#pragma unroll
            for (int j = 0; j < 8; ++j)
                bf[s][ct][j] = (__bf16)aw1[(s * 32 + q * 8 + j) * 64 + ct * 16 + m];

    // epilogue constants for this lane's 16 channels: ch = ct*16 + q*4 + r
    float ab1e[4][4], aw2e[4][4];
#pragma unroll
    for (int ct = 0; ct < 4; ++ct)
#pragma unroll
        for (int r = 0; r < 4; ++r) {
            int ch = ct * 16 + q * 4 + r;
            ab1e[ct][r] = ab1[ch];
            aw2e[ct][r] = aw2[ch];
        }
    const float ab2s = ab2[0];

    __bf16* Arow = A + ((size_t)(b * N_ + i) << 9);

#pragma unroll 1
    for (int t = 0; t < 32; ++t) {
        int j0 = t << 4;
        const float* cj = coords + (size_t)(b * N_ + j0 + m) * 3;
        float d0 = cj[0], d1 = cj[1], d2 = cj[2];

        // layer 0: h1[pair=m][ch], pair = j0+m, this lane's chs = {s*32+q*8+j}
        bf16x8 a0, a1;
#pragma unroll
        for (int j = 0; j < 8; ++j) {
            float v0 = fmaxf(o[0][j] + d0 * w3[0][j] + d1 * w4[0][j] + d2 * w5[0][j], 0.0f);
            float v1 = fmaxf(o[1][j] + d0 * w3[1][j] + d1 * w4[1][j] + d2 * w5[1][j], 0.0f);
            a0[j] = (__bf16)v0;
            a1[j] = (__bf16)v1;
        }

        // layer 1 transposed: D'[ch_local=q*4+r][pair=m] = H2[pair][ct*16+q*4+r]
        float p0, p1, p2, p3;
        {
            f32x4 c0v = {ab1e[0][0], ab1e[0][1], ab1e[0][2], ab1e[0][3]};
            c0v = __builtin_amdgcn_mfma_f32_16x16x32_bf16(bf[0][0], a0, c0v, 0, 0, 0);
            c0v = __builtin_amdgcn_mfma_f32_16x16x32_bf16(bf[1][0], a1, c0v, 0, 0, 0);
            f32x4 c1v = {ab1e[1][0], ab1e[1][1], ab1e[1][2], ab1e[1][3]};
            c1v = __builtin_amdgcn_mfma_f32_16x16x32_bf16(bf[0][1], a0, c1v, 0, 0, 0);
            c1v = __builtin_amdgcn_mfma_f32_16x16x32_bf16(bf[1][1], a1, c1v, 0, 0, 0);
            f32x4 c2v = {ab1e[2][0], ab1e[2][1], ab1e[2][2], ab1e[2][3]};
            c2v = __builtin_amdgcn_mfma_f32_16x16x32_bf16(bf[0][2], a0, c2v, 0, 0, 0);
            c2v = __builtin_amdgcn_mfma_f32_16x16x32_bf16(bf[1][2], a1, c2v, 0, 0, 0);
            f32x4 c3v = {ab1e[3][0], ab1e[3][1], ab1e[3][2], ab1e[3][3]};
            c3v = __builtin_amdgcn_mfma_f32_16x16x32_bf16(bf[0][3], a0, c3v, 0, 0, 0);
            c3v = __builtin_amdgcn_mfma_f32_16x16x32_bf16(bf[1][3], a1, c3v, 0, 0, 0);
            p0 = fmaxf(c0v[0], 0.f) * aw2e[0][0] + fmaxf(c0v[1], 0.f) * aw2e[0][1]
               + fmaxf(c0v[2], 0.f) * aw2e[0][2] + fmaxf(c0v[3], 0.f) * aw2e[0][3];
            p1 = fmaxf(c1v[0], 0.f) * aw2e[1][0] + fmaxf(c1v[1], 0.f) * aw2e[1][1]
               + fmaxf(c1v[2], 0.f) * aw2e[1][2] + fmaxf(c1v[3], 0.f) * aw2e[1][3];
            p2 = fmaxf(c2v[0], 0.f) * aw2e[2][0] + fmaxf(c2v[1], 0.f) * aw2e[2][1]
               + fmaxf(c2v[2], 0.f) * aw2e[2][2] + fmaxf(c2v[3], 0.f) * aw2e[2][3];
            p3 = fmaxf(c3v[0], 0.f) * aw2e[3][0] + fmaxf(c3v[1], 0.f) * aw2e[3][1]
               + fmaxf(c3v[2], 0.f) * aw2e[3][2] + fmaxf(c3v[3], 0.f) * aw2e[3][3];
        }
        float p = (p0 + p1) + (p2 + p3);
        // reduce over quads (lanes sharing m)
        p += __shfl_xor(p, 16, 64);
        p += __shfl_xor(p, 32, 64);
        if (l < 16) Arow[j0 + l] = (__bf16)fmaxf(ab2s + p, 0.0f);
    }
}

// ---------------- V = A @ h via bf16 MFMA -----------------------------------
// grid: B_*32 blocks of 256 thr; block = 16 rows x 128 cols; wave g owns
// n-tiles {2g, 2g+1}. A rows and h^T rows give direct 16B fragment loads.
__global__ __launch_bounds__(256) void k_aggregate(
    const __bf16* __restrict__ A, const __bf16* __restrict__ h_t,
    float* __restrict__ V)
{
    const int tid = threadIdx.x;
    const int l = tid & 63;
    const int g = tid >> 6;
    const int q = l >> 4;
    const int m = l & 15;
    const int b = blockIdx.x >> 5;
    const int row0 = (blockIdx.x & 31) << 4;

    const __bf16* Ar = A + ((size_t)b << 18) + (size_t)(row0 + m) * 512 + q * 8;
    const __bf16* h0 = h_t + ((size_t)b << 16) + (size_t)(32 * g + m) * 512 + q * 8;
    const __bf16* h1p = h0 + 16 * 512;

    f32x4 acc0 = {0.f, 0.f, 0.f, 0.f}, acc1 = {0.f, 0.f, 0.f, 0.f};
#pragma unroll 4
    for (int kt = 0; kt < 16; ++kt) {
        bf16x8 av = *(const bf16x8*)(Ar + kt * 32);
        bf16x8 b0 = *(const bf16x8*)(h0 + kt * 32);
        bf16x8 b1 = *(const bf16x8*)(h1p + kt * 32);
        acc0 = __builtin_amdgcn_mfma_f32_16x16x32_bf16(av, b0, acc0, 0, 0, 0);
        acc1 = __builtin_amdgcn_mfma_f32_16x16x32_bf16(av, b1, acc1, 0, 0, 0);
    }
    float* Vb = V + ((size_t)(b * N_ + row0) << 7);
#pragma unroll
    for (int r = 0; r < 4; ++r) {
        Vb[(size_t)(q * 4 + r) * 128 + 32 * g + m] = acc0[r];
        Vb[(size_t)(q * 4 + r) * 128 + 32 * g + m + 16] = acc1[r];
    }
}

// ---------------- update MLP (259 -> 256 -> 128) + max pool -----------------
// 512 blocks x 8 rows (wave g -> rows 2g, 2g+1). float4 weight loads, 8 in
// flight; activations broadcast from LDS. Block-level max then one atomic.
__global__ __launch_bounds__(256) void k_update(
    const float* __restrict__ h, const float* __restrict__ coords,
    const float* __restrict__ V,
    const float* __restrict__ uw0, const float* __restrict__ ub0,
    const float* __restrict__ uw1, const float* __restrict__ ub1,
    float* __restrict__ out)
{
    const int t = threadIdx.x;
    const int g = t >> 6;            // wave
    const int l = t & 63;
    const int row0 = blockIdx.x << 3;   // 8 rows, same b (512%8==0)
    const int b = row0 >> 9;

    __shared__ float upd[8][260];
    __shared__ float u1[8][260];

#pragma unroll 1
    for (int r = 0; r < 8; ++r) {
        int row = row0 + r;
        if (t < 128) {
            upd[r][t] = h[((size_t)row << 7) + t];
            upd[r][131 + t] = V[((size_t)row << 7) + t];
        } else if (t < 131) {
            upd[r][t] = coords[(size_t)row * 3 + (t - 128)];
        }
    }
    __syncthreads();

    const int r0 = g << 1;           // this wave's 2 rows
    // ---- layer 1: cols c0=4l..4l+3 ----
    const int c0 = l << 2;
    float acc[2][4];
#pragma unroll
    for (int c = 0; c < 4; ++c) {
        float bias = ub0[c0 + c];
        acc[0][c] = bias; acc[1][c] = bias;
    }
#pragma unroll 2
    for (int k = 0; k < 256; k += 4) {
        float4 w[4];
#pragma unroll
        for (int kk = 0; kk < 4; ++kk)
            w[kk] = *(const float4*)(uw0 + (size_t)(k + kk) * 256 + c0);
        float4 ua = *(const float4*)&upd[r0][k];
        float4 ub = *(const float4*)&upd[r0 + 1][k];
        acc[0][0] += ua.x * w[0].x + ua.y * w[1].x + ua.z * w[2].x + ua.w * w[3].x;
        acc[0][1] += ua.x * w[0].y + ua.y * w[1].y + ua.z * w[2].y + ua.w * w[3].y;
        acc[0][2] += ua.x * w[0].z + ua.y * w[1].z + ua.z * w[2].z + ua.w * w[3].z;
        acc[0][3] += ua.x * w[0].w + ua.y * w[1].w + ua.z * w[2].w + ua.w * w[3].w;
        acc[1][0] += ub.x * w[0].x + ub.y * w[1].x + ub.z * w[2].x + ub.w * w[3].x;
        acc[1][1] += ub.x * w[0].y + ub.y * w[1].y + ub.z * w[2].y + ub.w * w[3].y;
        acc[1][2] += ub.x * w[0].z + ub.y * w[1].z + ub.z * w[2].z + ub.w * w[3].z;
        acc[1][3] += ub.x * w[0].w + ub.y * w[1].w + ub.z * w[2].w + ub.w * w[3].w;
    }
#pragma unroll
    for (int k = 256; k < 259; ++k) {
        float4 w = *(const float4*)(uw0 + (size_t)k * 256 + c0);
        float uva = upd[r0][k], uvb = upd[r0 + 1][k];
        acc[0][0] += uva * w.x; acc[0][1] += uva * w.y;
        acc[0][2] += uva * w.z; acc[0][3] += uva * w.w;
        acc[1][0] += uvb * w.x; acc[1][1] += uvb * w.y;
        acc[1][2] += uvb * w.z; acc[1][3] += uvb * w.w;
    }
#pragma unroll
    for (int r = 0; r < 2; ++r) {
        float4 v;
        v.x = fmaxf(acc[r][0], 0.0f);
        v.y = fmaxf(acc[r][1], 0.0f);
        v.z = fmaxf(acc[r][2], 0.0f);
        v.w = fmaxf(acc[r][3], 0.0f);
        *(float4*)&u1[r0 + r][c0] = v;
    }
    __syncthreads();

    // ---- layer 2: cols c2=2l, 2l+1 ----
    const int c2 = l << 1;
    float a2[2][2];
    {
        float b0v = ub1[c2], b1v = ub1[c2 + 1];
        a2[0][0] = b0v; a2[0][1] = b1v;
        a2[1][0] = b0v; a2[1][1] = b1v;
    }
#pragma unroll 2
    for (int k = 0; k < 256; k += 4) {
        float2 w[4];
#pragma unroll
        for (int kk = 0; kk < 4; ++kk)
            w[kk] = *(const float2*)(uw1 + (size_t)(k + kk) * 128 + c2);
        float4 ua = *(const float4*)&u1[r0][k];
        float4 ub = *(const float4*)&u1[r0 + 1][k];
        a2[0][0] += ua.x * w[0].x + ua.y * w[1].x + ua.z * w[2].x + ua.w * w[3].x;
        a2[0][1] += ua.x * w[0].y + ua.y * w[1].y + ua.z * w[2].y + ua.w * w[3].y;
        a2[1][0] += ub.x * w[0].x + ub.y * w[1].x + ub.z * w[2].x + ub.w * w[3].x;
        a2[1][1] += ub.x * w[0].y + ub.y * w[1].y + ub.z * w[2].y + ub.w * w[3].y;
    }
    float m0 = fmaxf(fmaxf(a2[0][0], a2[1][0]), 0.0f);
    float m1 = fmaxf(fmaxf(a2[0][1], a2[1][1]), 0.0f);

    // cross-wave max in LDS (reuse upd area; layer-1 reads long done)
    float* red = &upd[0][0];
    red[g * 130 + c2] = m0;
    red[g * 130 + c2 + 1] = m1;
    __syncthreads();
    if (t < 128) {
        float mx = fmaxf(fmaxf(red[t], red[130 + t]),
                         fmaxf(red[260 + t], red[390 + t]));
        atomicMax((int*)(out + ((size_t)b << 7) + t), __float_as_int(mx));
    }
}

extern "C" void kernel_launch(void* const* d_in, const int* in_sizes, int n_in,
                              void* d_out, int out_size, void* d_ws, size_t ws_size,
                              hipStream_t stream)
{
    const float* coords = (const float*)d_in[0];
    const float* fw0 = (const float*)d_in[1];
    const float* fb0 = (const float*)d_in[2];
    const float* fw1 = (const float*)d_in[3];
    const float* fb1 = (const float*)d_in[4];
    const float* aw0 = (const float*)d_in[5];
    const float* ab0 = (const float*)d_in[6];
    const float* aw1 = (const float*)d_in[7];
    const float* ab1 = (const float*)d_in[8];
    const float* aw2 = (const float*)d_in[9];
    const float* ab2 = (const float*)d_in[10];
    const float* uw0 = (const float*)d_in[11];
    const float* ub0 = (const float*)d_in[12];
    const float* uw1 = (const float*)d_in[13];
    const float* ub1 = (const float*)d_in[14];
    float* out = (float*)d_out;

    // workspace layout
    char* ws = (char*)d_ws;
    float* h    = (float*)(ws);                      // B*N*128 fp32  = 2 MB
    __bf16* A   = (__bf16*)(ws + (2u << 20));        // B*N*N  bf16   = 4 MB
    float* V    = (float*)(ws + (6u << 20));         // B*N*128 fp32  = 2 MB
    __bf16* h_t = (__bf16*)(ws + (8u << 20));        // B*128*N bf16  = 1 MB

    k_zero<<<(out_size + 255) / 256, 256, 0, stream>>>(out, out_size);
    k_node_mlp<<<B_ * N_, 128, 0, stream>>>(coords, fw0, fb0, fw1, fb1, h, h_t);
    k_adj<<<B_ * N_ / 4, 256, 0, stream>>>(coords, aw0, ab0, aw1, ab1, aw2, ab2, A);
    k_aggregate<<<B_ * 32, 256, 0, stream>>>(A, h_t, V);
    k_update<<<B_ * N_ / 8, 256, 0, stream>>>(h, coords, V, uw0, ub0, uw1, ub1, out);
}

// Round 5
// 180.569 us; speedup vs baseline: 3.4220x; 1.1523x over previous
//
#include <hip/hip_runtime.h>
#include <hip/hip_bf16.h>

#define B_ 8
#define N_ 512
#define NN (N_*N_)

typedef __attribute__((ext_vector_type(8))) __bf16 bf16x8;
typedef __attribute__((ext_vector_type(4))) float f32x4;

// ---------------- zero the output (poisoned 0xAA before every launch) -------
__global__ void k_zero(float* __restrict__ out, int n) {
    int i = blockIdx.x * 256 + threadIdx.x;
    if (i < n) out[i] = 0.0f;
}

// ---------------- weight prep: bf16 transposed copies of uw0/uw1 ------------
// w0t[c][k] = uw0[perm(k)][c], perm(k) = k (<128, h part) else k+3 (V part).
// w1t[c][k] = uw1[k][c]. Coord rows 128..130 of uw0 stay fp32 (used in C-init).
__global__ __launch_bounds__(256) void k_prep(
    const float* __restrict__ uw0, const float* __restrict__ uw1,
    __bf16* __restrict__ w0t, __bf16* __restrict__ w1t)
{
    int id = blockIdx.x * 256 + threadIdx.x;    // 0..98303
    if (id < 65536) {
        int c = id >> 8, k = id & 255;
        int src = (k < 128) ? k : (k + 3);
        w0t[(size_t)c * 256 + k] = (__bf16)uw0[(size_t)src * 256 + c];
    } else {
        int id2 = id - 65536;
        int c = id2 >> 8, k = id2 & 255;
        w1t[(size_t)c * 256 + k] = (__bf16)uw1[(size_t)k * 128 + c];
    }
}

// ---------------- node feature MLP: (B*N,3) -> 64 -> 128  + g precompute ----
// writes h fp32, h^T bf16 (aggregate B-operand), and g[row][64] = c_j . aw0[3:6]
__global__ __launch_bounds__(128) void k_node_mlp(
    const float* __restrict__ coords,
    const float* __restrict__ fw0, const float* __restrict__ fb0,
    const float* __restrict__ fw1, const float* __restrict__ fb1,
    const float* __restrict__ aw0,
    float* __restrict__ h, __bf16* __restrict__ h_t, float* __restrict__ g)
{
    int row = blockIdx.x;          // b*512 + n
    int b = row >> 9;
    int n = row & 511;
    int t = threadIdx.x;           // 0..127
    __shared__ float c[3];
    __shared__ float hid[64];
    if (t < 3) c[t] = coords[row * 3 + t];
    __syncthreads();
    if (t < 64) {
        float v = fb0[t];
        v += c[0] * fw0[0 * 64 + t];
        v += c[1] * fw0[1 * 64 + t];
        v += c[2] * fw0[2 * 64 + t];
        hid[t] = fmaxf(v, 0.0f);
        // g: the c_j-dependent half of the adjacency layer-0 pre-activation
        g[((size_t)row << 6) + t] = c[0] * aw0[3 * 64 + t]
                                  + c[1] * aw0[4 * 64 + t]
                                  + c[2] * aw0[5 * 64 + t];
    }
    __syncthreads();
    float acc = fb1[t];
#pragma unroll
    for (int k = 0; k < 64; ++k) acc += hid[k] * fw1[k * 128 + t];
    float r = fmaxf(acc, 0.0f);
    h[(size_t)row * 128 + t] = r;
    h_t[(size_t)(b * 128 + t) * 512 + n] = (__bf16)r;
}

// ---------------- adjacency MLP via bf16 MFMA, transposed epilogue ----------
// layer 0 now: relu(o_i[ch] + g_j[ch]) -- g precomputed, 16 add + 16 max/lane.
__global__ __launch_bounds__(256) void k_adj(
    const float* __restrict__ coords, const float* __restrict__ g,
    const float* __restrict__ aw0, const float* __restrict__ ab0,
    const float* __restrict__ aw1, const float* __restrict__ ab1,
    const float* __restrict__ aw2, const float* __restrict__ ab2,
    __bf16* __restrict__ A)
{
    const int tid = threadIdx.x;
    const int l = tid & 63;          // lane
    const int wave = tid >> 6;       // 0..3
    const int q = l >> 4;            // quad 0..3
    const int m = l & 15;            // 0..15
    const int b = blockIdx.x >> 7;
    const int i = ((blockIdx.x & 127) << 2) + wave;

    // wave-uniform c_i folded into per-lane layer-0 offsets
    const float* ci = coords + (size_t)(b * N_ + i) * 3;
    const float ci0 = ci[0], ci1 = ci[1], ci2 = ci[2];

    float o[2][8];
#pragma unroll
    for (int s = 0; s < 2; ++s)
#pragma unroll
        for (int j = 0; j < 8; ++j) {
            int c = s * 32 + q * 8 + j;
            o[s][j] = ab0[c] + ci0 * aw0[0 * 64 + c] + ci1 * aw0[1 * 64 + c]
                             + ci2 * aw0[2 * 64 + c];
        }

    // aw1 fragments (A-operand of the transposed MFMA)
    bf16x8 bf[2][4];
#pragma unroll
    for (int s = 0; s < 2; ++s)
#pragma unroll
        for (int ct = 0; ct < 4; ++ct)
#pragma unroll
            for (int j = 0; j < 8; ++j)
                bf[s][ct][j] = (__bf16)aw1[(s * 32 + q * 8 + j) * 64 + ct * 16 + m];

    float ab1e[4][4], aw2e[4][4];
#pragma unroll
    for (int ct = 0; ct < 4; ++ct)
#pragma unroll
        for (int r = 0; r < 4; ++r) {
            int ch = ct * 16 + q * 4 + r;
            ab1e[ct][r] = ab1[ch];
            aw2e[ct][r] = aw2[ch];
        }
    const float ab2s = ab2[0];

    __bf16* Arow = A + ((size_t)(b * N_ + i) << 9);

#pragma unroll 1
    for (int t = 0; t < 32; ++t) {
        int j0 = t << 4;
        const float* grow = g + ((size_t)(b * N_ + j0 + m) << 6);
        f32x4 ga0 = *(const f32x4*)(grow + q * 8);
        f32x4 ga1 = *(const f32x4*)(grow + q * 8 + 4);
        f32x4 gb0 = *(const f32x4*)(grow + 32 + q * 8);
        f32x4 gb1 = *(const f32x4*)(grow + 32 + q * 8 + 4);

        bf16x8 a0, a1;
#pragma unroll
        for (int j = 0; j < 4; ++j) {
            a0[j]     = (__bf16)fmaxf(o[0][j]     + ga0[j], 0.0f);
            a0[4 + j] = (__bf16)fmaxf(o[0][4 + j] + ga1[j], 0.0f);
            a1[j]     = (__bf16)fmaxf(o[1][j]     + gb0[j], 0.0f);
            a1[4 + j] = (__bf16)fmaxf(o[1][4 + j] + gb1[j], 0.0f);
        }

        // layer 1 transposed: lane holds 16 output channels of ONE pair
        float p0, p1, p2, p3;
        {
            f32x4 c0v = {ab1e[0][0], ab1e[0][1], ab1e[0][2], ab1e[0][3]};
            c0v = __builtin_amdgcn_mfma_f32_16x16x32_bf16(bf[0][0], a0, c0v, 0, 0, 0);
            c0v = __builtin_amdgcn_mfma_f32_16x16x32_bf16(bf[1][0], a1, c0v, 0, 0, 0);
            f32x4 c1v = {ab1e[1][0], ab1e[1][1], ab1e[1][2], ab1e[1][3]};
            c1v = __builtin_amdgcn_mfma_f32_16x16x32_bf16(bf[0][1], a0, c1v, 0, 0, 0);
            c1v = __builtin_amdgcn_mfma_f32_16x16x32_bf16(bf[1][1], a1, c1v, 0, 0, 0);
            f32x4 c2v = {ab1e[2][0], ab1e[2][1], ab1e[2][2], ab1e[2][3]};
            c2v = __builtin_amdgcn_mfma_f32_16x16x32_bf16(bf[0][2], a0, c2v, 0, 0, 0);
            c2v = __builtin_amdgcn_mfma_f32_16x16x32_bf16(bf[1][2], a1, c2v, 0, 0, 0);
            f32x4 c3v = {ab1e[3][0], ab1e[3][1], ab1e[3][2], ab1e[3][3]};
            c3v = __builtin_amdgcn_mfma_f32_16x16x32_bf16(bf[0][3], a0, c3v, 0, 0, 0);
            c3v = __builtin_amdgcn_mfma_f32_16x16x32_bf16(bf[1][3], a1, c3v, 0, 0, 0);
            p0 = fmaxf(c0v[0], 0.f) * aw2e[0][0] + fmaxf(c0v[1], 0.f) * aw2e[0][1]
               + fmaxf(c0v[2], 0.f) * aw2e[0][2] + fmaxf(c0v[3], 0.f) * aw2e[0][3];
            p1 = fmaxf(c1v[0], 0.f) * aw2e[1][0] + fmaxf(c1v[1], 0.f) * aw2e[1][1]
               + fmaxf(c1v[2], 0.f) * aw2e[1][2] + fmaxf(c1v[3], 0.f) * aw2e[1][3];
            p2 = fmaxf(c2v[0], 0.f) * aw2e[2][0] + fmaxf(c2v[1], 0.f) * aw2e[2][1]
               + fmaxf(c2v[2], 0.f) * aw2e[2][2] + fmaxf(c2v[3], 0.f) * aw2e[2][3];
            p3 = fmaxf(c3v[0], 0.f) * aw2e[3][0] + fmaxf(c3v[1], 0.f) * aw2e[3][1]
               + fmaxf(c3v[2], 0.f) * aw2e[3][2] + fmaxf(c3v[3], 0.f) * aw2e[3][3];
        }
        float p = (p0 + p1) + (p2 + p3);
        p += __shfl_xor(p, 16, 64);
        p += __shfl_xor(p, 32, 64);
        if (l < 16) Arow[j0 + l] = (__bf16)fmaxf(ab2s + p, 0.0f);
    }
}

// ---------------- V = A @ h via bf16 MFMA (unchanged from R4) ---------------
__global__ __launch_bounds__(256) void k_aggregate(
    const __bf16* __restrict__ A, const __bf16* __restrict__ h_t,
    float* __restrict__ V)
{
    const int tid = threadIdx.x;
    const int l = tid & 63;
    const int g = tid >> 6;
    const int q = l >> 4;
    const int m = l & 15;
    const int b = blockIdx.x >> 5;
    const int row0 = (blockIdx.x & 31) << 4;

    const __bf16* Ar = A + ((size_t)b << 18) + (size_t)(row0 + m) * 512 + q * 8;
    const __bf16* h0 = h_t + ((size_t)b << 16) + (size_t)(32 * g + m) * 512 + q * 8;
    const __bf16* h1p = h0 + 16 * 512;

    f32x4 acc0 = {0.f, 0.f, 0.f, 0.f}, acc1 = {0.f, 0.f, 0.f, 0.f};
#pragma unroll 4
    for (int kt = 0; kt < 16; ++kt) {
        bf16x8 av = *(const bf16x8*)(Ar + kt * 32);
        bf16x8 b0 = *(const bf16x8*)(h0 + kt * 32);
        bf16x8 b1 = *(const bf16x8*)(h1p + kt * 32);
        acc0 = __builtin_amdgcn_mfma_f32_16x16x32_bf16(av, b0, acc0, 0, 0, 0);
        acc1 = __builtin_amdgcn_mfma_f32_16x16x32_bf16(av, b1, acc1, 0, 0, 0);
    }
    float* Vb = V + ((size_t)(b * N_ + row0) << 7);
#pragma unroll
    for (int r = 0; r < 4; ++r) {
        Vb[(size_t)(q * 4 + r) * 128 + 32 * g + m] = acc0[r];
        Vb[(size_t)(q * 4 + r) * 128 + 32 * g + m + 16] = acc1[r];
    }
}

// ---------------- update MLP (259 -> 256 -> 128) via MFMA + max pool --------
// 256 blocks x 512 thr (8 waves, 2/SIMD), 16 rows/block.
// K permuted to [h(128) | V(128)]; coord rows + bias fold into fp32 C-init.
// Layer 1: 16 col-tiles (2/wave); layer 2: 8 col-tiles (1/wave).
__global__ __launch_bounds__(512) void k_update(
    const float* __restrict__ h, const float* __restrict__ coords,
    const float* __restrict__ V,
    const float* __restrict__ uw0, const float* __restrict__ ub0,
    const __bf16* __restrict__ w0t, const __bf16* __restrict__ w1t,
    const float* __restrict__ ub1,
    float* __restrict__ out)
{
    const int t = threadIdx.x;
    const int g = t >> 6;            // wave 0..7
    const int l = t & 63;
    const int q = l >> 4;
    const int m = l & 15;
    const int row0 = blockIdx.x << 4;   // 16 rows, same b
    const int b = row0 >> 9;

    __shared__ __align__(16) __bf16 act[16][256];  // [row][k], k=[h|V]
    __shared__ __align__(16) __bf16 u1[16][256];
    __shared__ float cds[16][4];

#pragma unroll 1
    for (int r = 0; r < 16; ++r) {
        int row = row0 + r;
        if (t < 128) act[r][t] = (__bf16)h[((size_t)row << 7) + t];
        else if (t < 256) act[r][t] = (__bf16)V[((size_t)row << 7) + (t - 128)];
    }
    if (t < 48) {
        int r = t / 3, d = t - 3 * r;
        cds[r][d] = coords[(size_t)(row0 + r) * 3 + d];
    }
    __syncthreads();

    // A-fragments for layer 1 (shared across this wave's col tiles)
    bf16x8 af[8];
#pragma unroll
    for (int ch = 0; ch < 8; ++ch)
        af[ch] = *(const bf16x8*)&act[m][q * 8 + 32 * ch];

    // ---- layer 1: this wave's col tiles ct = 0,1 -> cols g*32+ct*16+m ----
#pragma unroll
    for (int ct = 0; ct < 2; ++ct) {
        const int c = g * 32 + ct * 16 + m;
        const float wx = uw0[128 * 256 + c];
        const float wy = uw0[129 * 256 + c];
        const float wz = uw0[130 * 256 + c];
        const float bias = ub0[c];
        f32x4 acc;
#pragma unroll
        for (int r = 0; r < 4; ++r)
            acc[r] = bias + cds[q * 4 + r][0] * wx + cds[q * 4 + r][1] * wy
                          + cds[q * 4 + r][2] * wz;
        const __bf16* wp = w0t + (size_t)c * 256 + q * 8;
#pragma unroll
        for (int ch = 0; ch < 8; ++ch) {
            bf16x8 bfr = *(const bf16x8*)(wp + 32 * ch);
            acc = __builtin_amdgcn_mfma_f32_16x16x32_bf16(af[ch], bfr, acc, 0, 0, 0);
        }
#pragma unroll
        for (int r = 0; r < 4; ++r)
            u1[q * 4 + r][c] = (__bf16)fmaxf(acc[r], 0.0f);
    }
    __syncthreads();

    // ---- layer 2: this wave's col tile -> cols g*16+m ----
    bf16x8 af2[8];
#pragma unroll
    for (int ch = 0; ch < 8; ++ch)
        af2[ch] = *(const bf16x8*)&u1[m][q * 8 + 32 * ch];
    {
        const int c = g * 16 + m;
        float bias = ub1[c];
        f32x4 acc = {bias, bias, bias, bias};
        const __bf16* wp = w1t + (size_t)c * 256 + q * 8;
#pragma unroll
        for (int ch = 0; ch < 8; ++ch) {
            bf16x8 bfr = *(const bf16x8*)(wp + 32 * ch);
            acc = __builtin_amdgcn_mfma_f32_16x16x32_bf16(af2[ch], bfr, acc, 0, 0, 0);
        }
        float mx = fmaxf(fmaxf(acc[0], acc[1]), fmaxf(acc[2], acc[3]));
        mx = fmaxf(mx, 0.0f);
        mx = fmaxf(mx, __shfl_xor(mx, 16, 64));
        mx = fmaxf(mx, __shfl_xor(mx, 32, 64));
        if (l < 16)
            atomicMax((int*)(out + ((size_t)b << 7) + c), __float_as_int(mx));
    }
}

extern "C" void kernel_launch(void* const* d_in, const int* in_sizes, int n_in,
                              void* d_out, int out_size, void* d_ws, size_t ws_size,
                              hipStream_t stream)
{
    const float* coords = (const float*)d_in[0];
    const float* fw0 = (const float*)d_in[1];
    const float* fb0 = (const float*)d_in[2];
    const float* fw1 = (const float*)d_in[3];
    const float* fb1 = (const float*)d_in[4];
    const float* aw0 = (const float*)d_in[5];
    const float* ab0 = (const float*)d_in[6];
    const float* aw1 = (const float*)d_in[7];
    const float* ab1 = (const float*)d_in[8];
    const float* aw2 = (const float*)d_in[9];
    const float* ab2 = (const float*)d_in[10];
    const float* uw0 = (const float*)d_in[11];
    const float* ub0 = (const float*)d_in[12];
    const float* uw1 = (const float*)d_in[13];
    const float* ub1 = (const float*)d_in[14];
    float* out = (float*)d_out;

    // workspace layout
    char* ws = (char*)d_ws;
    float* h    = (float*)(ws);                        // 2 MB fp32
    __bf16* A   = (__bf16*)(ws + (2u << 20));          // 4 MB bf16
    float* V    = (float*)(ws + (6u << 20));           // 2 MB fp32
    __bf16* h_t = (__bf16*)(ws + (8u << 20));          // 1 MB bf16
    float* g    = (float*)(ws + (9u << 20));           // 1 MB fp32
    __bf16* w0t = (__bf16*)(ws + (10u << 20));         // 128 KB
    __bf16* w1t = (__bf16*)(ws + (10u << 20) + (128u << 10)); // 64 KB

    k_zero<<<(out_size + 255) / 256, 256, 0, stream>>>(out, out_size);
    k_prep<<<384, 256, 0, stream>>>(uw0, uw1, w0t, w1t);
    k_node_mlp<<<B_ * N_, 128, 0, stream>>>(coords, fw0, fb0, fw1, fb1, aw0, h, h_t, g);
    k_adj<<<B_ * N_ / 4, 256, 0, stream>>>(coords, g, aw0, ab0, aw1, ab1, aw2, ab2, A);
    k_aggregate<<<B_ * 32, 256, 0, stream>>>(A, h_t, V);
    k_update<<<B_ * N_ / 16, 512, 0, stream>>>(h, coords, V, uw0, ub0, w0t, w1t, ub1, out);
}